// Round 1
// baseline (141.869 us; speedup 1.0000x reference)
//
#include <hip/hip_runtime.h>
#include <hip/hip_bf16.h>
#include <math.h>

#define NB 8
#define SQ 2048
#define EMB 256
#define DK 64
#define HID 64

typedef __attribute__((ext_vector_type(8))) short short8;
typedef __attribute__((ext_vector_type(4))) float f32x4;

__device__ __forceinline__ short f2bf(float f) {
    union { float f; unsigned u; } v; v.f = f;
    unsigned r = v.u + 0x7FFF + ((v.u >> 16) & 1);  // RNE
    return (short)(r >> 16);
}

// ---------------- K0a: obs fp32 -> bf16 ----------------
__global__ __launch_bounds__(256) void k_cvt_obs(const float* __restrict__ obs,
                                                 short* __restrict__ out, int n) {
    int i = (blockIdx.x * 256 + threadIdx.x) * 4;
    if (i >= n) return;
    float4 v = *(const float4*)(obs + i);
    short4 o;
    o.x = f2bf(v.x); o.y = f2bf(v.y); o.z = f2bf(v.z); o.w = f2bf(v.w);
    *(short4*)(out + i) = o;
}

// ---------------- K0b: build WT bf16 [192][256]  (rows 0-63 Wq, 64-127 Wk, 128-191 Wv)
__global__ __launch_bounds__(256) void k_wt(const float* __restrict__ Wq,
                                            const float* __restrict__ Wk,
                                            const float* __restrict__ Wv,
                                            short* __restrict__ wt) {
    int o = blockIdx.x * 256 + threadIdx.x;   // < 192*256
    int row = o >> 8, e = o & 255;
    int w = row >> 6, d = row & 63;
    const float* W = (w == 0) ? Wq : ((w == 1) ? Wk : Wv);
    wt[o] = f2bf(W[e * 64 + d]);
}

// ---------------- K1: fused projection GEMM [16384x256]@[256x192] -> q,k (scaled, row-major bf16), vT
__global__ __launch_bounds__(256) void k_proj(const short* __restrict__ obsb,
                                              const short* __restrict__ wt,
                                              short* __restrict__ qw,
                                              short* __restrict__ kw,
                                              short* __restrict__ vt) {
    int tid = threadIdx.x, w = tid >> 6, l = tid & 63;
    int rb = blockIdx.x;                 // 64 rows per block
    int r0 = rb * 64 + w * 16;
    int arow = r0 + (l & 15);
    int eo = (l >> 4) * 8;
    f32x4 acc[12];
    #pragma unroll
    for (int c = 0; c < 12; ++c) acc[c] = (f32x4){0.f, 0.f, 0.f, 0.f};
    #pragma unroll
    for (int ks = 0; ks < 8; ++ks) {
        int e0 = ks * 32;
        short8 a = *(const short8*)(obsb + (size_t)arow * 256 + e0 + eo);
        #pragma unroll
        for (int c = 0; c < 12; ++c) {
            short8 bf = *(const short8*)(wt + (size_t)(c * 16 + (l & 15)) * 256 + e0 + eo);
            acc[c] = __builtin_amdgcn_mfma_f32_16x16x32_bf16(a, bf, acc[c], 0, 0, 0);
        }
    }
    const float scale = 0.35355339059327373f;  // 64^-0.25
    __shared__ short ldsv[64][72];
    int rloc = w * 16 + (l >> 4) * 4;
    int col16 = l & 15;
    #pragma unroll
    for (int c = 0; c < 12; ++c) {
        #pragma unroll
        for (int r = 0; r < 4; ++r) {
            float val = acc[c][r];
            int row = r0 + (l >> 4) * 4 + r;
            if (c < 4) {
                qw[(size_t)row * 64 + c * 16 + col16] = f2bf(val * scale);
            } else if (c < 8) {
                kw[(size_t)row * 64 + (c - 4) * 16 + col16] = f2bf(val * scale);
            } else {
                ldsv[(c - 8) * 16 + col16][rloc + r] = f2bf(val);
            }
        }
    }
    __syncthreads();
    int b = (rb * 64) >> 11;
    int s0 = (rb * 64) & 2047;
    int d = tid >> 2, ch = (tid & 3) * 16;
    short* dst = vt + (size_t)b * 64 * 2048 + (size_t)d * 2048 + s0 + ch;
    #pragma unroll
    for (int j = 0; j < 16; ++j) dst[j] = ldsv[d][ch + j];
}

// ---------------- K2: QK^T lower-triangle tiles, raw scores -> attn slot
__global__ __launch_bounds__(256) void k_qkt(const short* __restrict__ qw,
                                             const short* __restrict__ kw,
                                             float* __restrict__ attn) {
    int t = blockIdx.x;   // 0..527 triangular tile index
    int b = blockIdx.y;
    int qb = (int)((sqrtf(8.f * t + 1.f) - 1.f) * 0.5f);
    while ((qb + 1) * (qb + 2) / 2 <= t) qb++;
    while (qb * (qb + 1) / 2 > t) qb--;
    int kb = t - qb * (qb + 1) / 2;
    int q0 = qb * 64, k0 = kb * 64;
    int tid = threadIdx.x, w = tid >> 6, l = tid & 63;
    int wr = w >> 1, wc = w & 1;
    int eo = (l >> 4) * 8;
    const short* qbase = qw + (size_t)b * SQ * 64;
    const short* kbase = kw + (size_t)b * SQ * 64;
    f32x4 acc[2][2];
    #pragma unroll
    for (int mi = 0; mi < 2; ++mi)
        #pragma unroll
        for (int nj = 0; nj < 2; ++nj) acc[mi][nj] = (f32x4){0.f, 0.f, 0.f, 0.f};
    #pragma unroll
    for (int ks = 0; ks < 2; ++ks) {
        short8 a[2], bb[2];
        #pragma unroll
        for (int mi = 0; mi < 2; ++mi)
            a[mi] = *(const short8*)(qbase + (size_t)(q0 + wr * 32 + mi * 16 + (l & 15)) * 64 + ks * 32 + eo);
        #pragma unroll
        for (int nj = 0; nj < 2; ++nj)
            bb[nj] = *(const short8*)(kbase + (size_t)(k0 + wc * 32 + nj * 16 + (l & 15)) * 64 + ks * 32 + eo);
        #pragma unroll
        for (int mi = 0; mi < 2; ++mi)
            #pragma unroll
            for (int nj = 0; nj < 2; ++nj)
                acc[mi][nj] = __builtin_amdgcn_mfma_f32_16x16x32_bf16(a[mi], bb[nj], acc[mi][nj], 0, 0, 0);
    }
    float* abase = attn + (size_t)b * SQ * SQ;
    #pragma unroll
    for (int mi = 0; mi < 2; ++mi)
        #pragma unroll
        for (int nj = 0; nj < 2; ++nj)
            #pragma unroll
            for (int r = 0; r < 4; ++r) {
                int row = q0 + wr * 32 + mi * 16 + (l >> 4) * 4 + r;
                int col = k0 + wc * 32 + nj * 16 + (l & 15);
                abase[(size_t)row * SQ + col] = acc[mi][nj][r];
            }
}

// ---------------- K3: causal row softmax in-place (row in registers)
__global__ __launch_bounds__(256) void k_softmax(float* __restrict__ attn) {
    int q = blockIdx.x, b = blockIdx.y;
    int tid = threadIdx.x, w = tid >> 6, l = tid & 63;
    float* row = attn + ((size_t)b * SQ + q) * SQ;
    int c0 = tid * 8;
    float4 v0 = *(const float4*)(row + c0);
    float4 v1 = *(const float4*)(row + c0 + 4);
    float s[8] = {v0.x, v0.y, v0.z, v0.w, v1.x, v1.y, v1.z, v1.w};
    float lm = -INFINITY;
    #pragma unroll
    for (int j = 0; j < 8; ++j) {
        if (c0 + j > q) s[j] = -INFINITY;   // mask before use; garbage never enters math
        lm = fmaxf(lm, s[j]);
    }
    #pragma unroll
    for (int o = 32; o > 0; o >>= 1) lm = fmaxf(lm, __shfl_xor(lm, o));
    __shared__ float red[8];
    if (l == 0) red[w] = lm;
    __syncthreads();
    float m = fmaxf(fmaxf(red[0], red[1]), fmaxf(red[2], red[3]));
    float ls = 0.f;
    #pragma unroll
    for (int j = 0; j < 8; ++j) { s[j] = __expf(s[j] - m); ls += s[j]; }
    #pragma unroll
    for (int o = 32; o > 0; o >>= 1) ls += __shfl_xor(ls, o);
    if (l == 0) red[4 + w] = ls;
    __syncthreads();
    float tot = red[4] + red[5] + red[6] + red[7];
    float inv = 1.f / tot;
    float4 o0, o1;
    o0.x = s[0] * inv; o0.y = s[1] * inv; o0.z = s[2] * inv; o0.w = s[3] * inv;
    o1.x = s[4] * inv; o1.y = s[5] * inv; o1.z = s[6] * inv; o1.w = s[7] * inv;
    *(float4*)(row + c0) = o0;
    *(float4*)(row + c0 + 4) = o1;
}

// ---------------- K4: PV = attn @ v  (bf16 MFMA, causal-clipped K loop)
__global__ __launch_bounds__(256) void k_pv(const float* __restrict__ attn,
                                            const short* __restrict__ vt,
                                            float* __restrict__ ao) {
    int rb = blockIdx.x, b = blockIdx.y;
    int q0 = rb * 64;
    int tid = threadIdx.x, w = tid >> 6, l = tid & 63;
    int r0 = q0 + w * 16;
    const float* abase = attn + (size_t)b * SQ * SQ;
    const short* vbase = vt + (size_t)b * 64 * SQ;
    int eo = (l >> 4) * 8;
    f32x4 acc[4];
    #pragma unroll
    for (int nj = 0; nj < 4; ++nj) acc[nj] = (f32x4){0.f, 0.f, 0.f, 0.f};
    int arow = r0 + (l & 15);
    int kmax = q0 + 64;
    for (int k0 = 0; k0 < kmax; k0 += 32) {
        const float* ap = abase + (size_t)arow * SQ + k0 + eo;
        float4 a0 = *(const float4*)ap;
        float4 a1 = *(const float4*)(ap + 4);
        short8 af;
        af[0] = f2bf(a0.x); af[1] = f2bf(a0.y); af[2] = f2bf(a0.z); af[3] = f2bf(a0.w);
        af[4] = f2bf(a1.x); af[5] = f2bf(a1.y); af[6] = f2bf(a1.z); af[7] = f2bf(a1.w);
        #pragma unroll
        for (int nj = 0; nj < 4; ++nj) {
            short8 bf = *(const short8*)(vbase + (size_t)(nj * 16 + (l & 15)) * SQ + k0 + eo);
            acc[nj] = __builtin_amdgcn_mfma_f32_16x16x32_bf16(af, bf, acc[nj], 0, 0, 0);
        }
    }
    #pragma unroll
    for (int nj = 0; nj < 4; ++nj)
        #pragma unroll
        for (int r = 0; r < 4; ++r) {
            size_t grow = (size_t)b * SQ + r0 + (l >> 4) * 4 + r;
            ao[grow * 64 + nj * 16 + (l & 15)] = acc[nj][r];
        }
}

// ---------------- K5: MLP  x = relu(ao@W1+b1)@W2+b2
__global__ __launch_bounds__(256) void k_mlp(const float* __restrict__ ao,
                                             const float* __restrict__ W1,
                                             const float* __restrict__ b1,
                                             const float* __restrict__ W2,
                                             const float* __restrict__ b2,
                                             float* __restrict__ x) {
    int tid = threadIdx.x, w = tid >> 6, l = tid & 63;
    int grow = blockIdx.x * 4 + w;
    __shared__ float lds[4][64];
    lds[w][l] = ao[(size_t)grow * 64 + l];
    __syncthreads();
    float acc = b1[l];
    #pragma unroll
    for (int d = 0; d < 64; ++d) acc += lds[w][d] * W1[d * 64 + l];
    float h = fmaxf(acc, 0.f);
    float p = h * W2[l];
    #pragma unroll
    for (int o = 32; o > 0; o >>= 1) p += __shfl_xor(p, o);
    if (l == 0) x[grow] = p + b2[0];
}

extern "C" void kernel_launch(void* const* d_in, const int* in_sizes, int n_in,
                              void* d_out, int out_size, void* d_ws, size_t ws_size,
                              hipStream_t stream) {
    const float* obs = (const float*)d_in[0];
    const float* Wq  = (const float*)d_in[2];
    const float* Wk  = (const float*)d_in[3];
    const float* Wv  = (const float*)d_in[4];
    const float* W1  = (const float*)d_in[5];
    const float* b1  = (const float*)d_in[6];
    const float* W2  = (const float*)d_in[7];
    const float* b2  = (const float*)d_in[8];

    float* x    = (float*)d_out;                    // [16384]
    float* attn = (float*)d_out + NB * SQ;          // [8][2048][2048]

    char* ws = (char*)d_ws;
    short* obsb = (short*)(ws);                     // 16384*256 bf16 = 8 MiB
    short* wt   = (short*)(ws + 8388608);           // 192*256 bf16
    short* qw   = (short*)(ws + 8486912);           // 16384*64 bf16
    short* kw   = (short*)(ws + 10584064);          // 16384*64 bf16
    short* vt   = (short*)(ws + 12681216);          // 8*64*2048 bf16
    float* ao   = (float*)(ws + 14778368);          // 16384*64 f32

    k_cvt_obs<<<dim3(4096), dim3(256), 0, stream>>>(obs, obsb, NB * SQ * EMB);
    k_wt<<<dim3(192), dim3(256), 0, stream>>>(Wq, Wk, Wv, wt);
    k_proj<<<dim3(256), dim3(256), 0, stream>>>(obsb, wt, qw, kw, vt);
    k_qkt<<<dim3(528, NB), dim3(256), 0, stream>>>(qw, kw, attn);
    k_softmax<<<dim3(SQ, NB), dim3(256), 0, stream>>>(attn);
    k_pv<<<dim3(32, NB), dim3(256), 0, stream>>>(attn, vt, ao);
    k_mlp<<<dim3(4096), dim3(256), 0, stream>>>(ao, W1, b1, W2, b2, x);
}